// Round 1
// 1646.855 us; speedup vs baseline: 1.0427x; 1.0427x over previous
//
#include <hip/hip_runtime.h>
#include <hip/hip_bf16.h>
#include <math.h>

constexpr int B = 64, N = 307, F = 64, T = 12, K = 3, C = 64, CT = 64;
constexpr float LN_EPS = 1e-5f;
constexpr int FT = F * T;  // 768

// ---------------- temporal attention ----------------

// lhs1_e[b,t,f] = sum_n x[b,n,f,t] * U1[n]
__global__ void k_lhs1_e(const float* __restrict__ x, const float* __restrict__ U1,
                         float* __restrict__ out) {
    int idx = blockIdx.x * blockDim.x + threadIdx.x;
    if (idx >= B * T * F) return;
    int f = idx % F;
    int t = (idx / F) % T;
    int b = idx / (F * T);
    const float* xp = x + ((size_t)b * N * F + f) * T + t;
    float s = 0.f;
    for (int n = 0; n < N; n++) s += xp[(size_t)n * F * T] * U1[n];
    out[idx] = s;
}

// fused: rhs_e[b,n,t] = sum_f U3[f]*x[b,n,f,t];  xw3[b,n,t] = sum_f W3[f]*x[b,n,f,t]
__global__ void k_xdots(const float* __restrict__ x, const float* __restrict__ U3,
                        const float* __restrict__ W3, float* __restrict__ rhs_e,
                        float* __restrict__ xw3) {
    int idx = blockIdx.x * blockDim.x + threadIdx.x;
    if (idx >= B * N * T) return;
    int t = idx % T;
    size_t bn = idx / T;
    const float* xp = x + bn * F * T + t;
    float s1 = 0.f, s2 = 0.f;
    for (int f = 0; f < F; f++) {
        float v = xp[f * T];
        s1 += U3[f] * v;
        s2 += W3[f] * v;
    }
    rhs_e[idx] = s1;
    xw3[idx] = s2;
}

// lhs_e[b,t,n] = sum_f lhs1_e[b,t,f] * U2[f,n]
__global__ void k_lhs_e(const float* __restrict__ lhs1, const float* __restrict__ U2,
                        float* __restrict__ out) {
    int idx = blockIdx.x * blockDim.x + threadIdx.x;
    if (idx >= B * T * N) return;
    int n = idx % N;
    int bt = idx / N;
    const float* lp = lhs1 + (size_t)bt * F;
    float s = 0.f;
    for (int f = 0; f < F; f++) s += lp[f] * U2[f * N + n];
    out[idx] = s;
}

// prod/sigmoid/V_e/softmax fused per batch: E[b,u,t] softmaxed over u
__global__ void k_tatt(const float* __restrict__ lhs, const float* __restrict__ rhs,
                       const float* __restrict__ b_e, const float* __restrict__ V_e,
                       float* __restrict__ E) {
    int b = blockIdx.x;
    int tid = threadIdx.x;
    __shared__ float sig[T * T];
    __shared__ float Ev[T * T];
    __shared__ float mx[T], sm[T];
    if (tid < T * T) {
        int t = tid % T, u = tid / T;
        const float* lp = lhs + ((size_t)b * T + u) * N;
        const float* rp = rhs + (size_t)b * N * T + t;
        float s = 0.f;
        for (int n = 0; n < N; n++) s += lp[n] * rp[(size_t)n * T];
        s += b_e[u * T + t];
        sig[tid] = 1.f / (1.f + expf(-s));
    }
    __syncthreads();
    if (tid < T * T) {
        int t = tid % T, u = tid / T;
        float e = 0.f;
        for (int v = 0; v < T; v++) e += V_e[u * T + v] * sig[v * T + t];
        Ev[tid] = e;
    }
    __syncthreads();
    if (tid < T) {
        float m = -1e30f;
        for (int u = 0; u < T; u++) m = fmaxf(m, Ev[u * T + tid]);
        float s = 0.f;
        for (int u = 0; u < T; u++) s += expf(Ev[u * T + tid] - m);
        mx[tid] = m;
        sm[tid] = s;
    }
    __syncthreads();
    if (tid < T * T) {
        int t = tid % T;
        E[(size_t)b * T * T + tid] = expf(Ev[tid] - mx[t]) / sm[t];
    }
}

// EW1[b,tp] = sum_t E[b,tp,t] * W1[t]
__global__ void k_EW1(const float* __restrict__ E, const float* __restrict__ W1,
                      float* __restrict__ out) {
    int idx = blockIdx.x * blockDim.x + threadIdx.x;
    if (idx >= B * T) return;
    const float* Ep = E + (size_t)idx * T;
    float s = 0.f;
    for (int t = 0; t < T; t++) s += Ep[t] * W1[t];
    out[idx] = s;
}

// ---------------- spatial attention (x_TAt folded in algebraically) ----------------

// lhs_s[b,n,t] = sum_f (sum_tp x[b,n,f,tp]*EW1[b,tp]) * W2[f,t]
__global__ void k_lhs_sf(const float* __restrict__ x, const float* __restrict__ EW1,
                         const float* __restrict__ W2, float* __restrict__ lhs_s) {
    int bn = blockIdx.x;
    int b = bn / N;
    int tid = threadIdx.x;  // 64
    __shared__ float a[F];
    __shared__ float ew[T];
    if (tid < T) ew[tid] = EW1[(size_t)b * T + tid];
    __syncthreads();
    const float* xp = x + (size_t)bn * F * T + tid * T;  // row f = tid
    float s = 0.f;
    for (int tp = 0; tp < T; tp++) s += xp[tp] * ew[tp];
    a[tid] = s;
    __syncthreads();
    if (tid < T) {
        float s2 = 0.f;
        for (int f = 0; f < F; f++) s2 += a[f] * W2[f * T + tid];
        lhs_s[(size_t)bn * T + tid] = s2;
    }
}

// rhs_s[b,t,m] = sum_tp xw3[b,m,tp] * E[b,tp,t]
__global__ void k_rhs_s2(const float* __restrict__ xw3, const float* __restrict__ E,
                         float* __restrict__ out) {
    int idx = blockIdx.x * blockDim.x + threadIdx.x;
    if (idx >= B * T * N) return;
    int m = idx % N;
    int t = (idx / N) % T;
    int b = idx / (N * T);
    const float* xp = xw3 + ((size_t)b * N + m) * T;
    const float* Ep = E + (size_t)b * T * T + t;
    float s = 0.f;
    for (int tp = 0; tp < T; tp++) s += xp[tp] * Ep[tp * T];
    out[idx] = s;
}

// VsT[v,i] = V_s[i,v]
__global__ void k_transposeVs(const float* __restrict__ V, float* __restrict__ VT) {
    int idx = blockIdx.x * blockDim.x + threadIdx.x;
    if (idx >= N * N) return;
    int v = idx % N;
    int i = idx / N;
    VT[(size_t)v * N + i] = V[(size_t)i * N + v];
}

// twT[dt][ct][c] = tw[ct][c][dt]  (contiguous-c for float4 loads in k_rest)
__global__ void k_twT(const float* __restrict__ tw, float* __restrict__ twT) {
    int idx = blockIdx.x * blockDim.x + threadIdx.x;
    if (idx >= CT * C * 3) return;
    int dt = idx % 3;
    int c = (idx / 3) % C;
    int ct = idx / (3 * C);
    twT[((size_t)dt * CT + ct) * C + c] = tw[idx];
}

// ThT[k][c][f] = Theta[k][f][c]  (contiguous-f for float4 loads in gcnz stage-2)
__global__ void k_thT(const float* __restrict__ Th, float* __restrict__ ThT) {
    int idx = blockIdx.x * blockDim.x + threadIdx.x;
    if (idx >= K * F * C) return;
    int c = idx % C;
    int f = (idx / C) % F;
    int k = idx / (C * F);
    ThT[((size_t)k * C + c) * F + f] = Th[idx];
}

// fused sigmoid + V_s projection, AT=4 rows per block for VsT reuse
constexpr int AT = 4;
constexpr int NAB = (N + AT - 1) / AT;  // 77

__global__ void k_sigS(const float* __restrict__ lhs_s, const float* __restrict__ rhs_s,
                       const float* __restrict__ b_s, const float* __restrict__ VsT,
                       float* __restrict__ S) {
    int blk = blockIdx.x;
    int b = blk / NAB;
    int a0 = (blk % NAB) * AT;
    int tid = threadIdx.x;  // 256
    __shared__ float lrow[AT][T];
    __shared__ float sig4[AT][N];
    if (tid < AT * T) {
        int a = tid / T, t = tid % T;
        lrow[a][t] = (a0 + a < N) ? lhs_s[((size_t)b * N + a0 + a) * T + t] : 0.f;
    }
    __syncthreads();
    for (int v = tid; v < N; v += 256) {
        float rv[T];
        for (int t = 0; t < T; t++) rv[t] = rhs_s[((size_t)b * T + t) * N + v];
        for (int a = 0; a < AT; a++) {
            if (a0 + a >= N) break;
            float s = 0.f;
            for (int t = 0; t < T; t++) s += lrow[a][t] * rv[t];
            s += b_s[(size_t)(a0 + a) * N + v];
            sig4[a][v] = 1.f / (1.f + expf(-s));
        }
    }
    __syncthreads();
    for (int i = tid; i < N; i += 256) {
        float s[AT] = {0.f, 0.f, 0.f, 0.f};
        for (int v = 0; v < N; v++) {
            float vt = VsT[(size_t)v * N + i];
            for (int a = 0; a < AT; a++) s[a] += sig4[a][v] * vt;
        }
        for (int a = 0; a < AT; a++)
            if (a0 + a < N) S[((size_t)b * N + a0 + a) * N + i] = s[a];
    }
}

// softmax over a (axis 1) for each (b, i) — lanes span consecutive i => coalesced
__global__ void k_softmax_S(float* __restrict__ S) {
    int idx = blockIdx.x * blockDim.x + threadIdx.x;
    if (idx >= B * N) return;
    int b = idx / N;
    int i = idx % N;
    float* p = S + (size_t)b * N * N + i;
    float m = -1e30f;
    for (int a = 0; a < N; a++) m = fmaxf(m, p[(size_t)a * N]);
    float s = 0.f;
    for (int a = 0; a < N; a++) s += expf(p[(size_t)a * N] - m);
    float inv = 1.f / s;
    for (int a = 0; a < N; a++) p[(size_t)a * N] = expf(p[(size_t)a * N] - m) * inv;
}

// ---------------- chebyshev graph conv + Theta + relu -> sg (in d_out) ----------------

constexpr int JT = 4;
constexpr int NJB = (N + JT - 1) / JT;  // 77
constexpr int FP = F + 1;               // 65: per-t bank shift of 4 on zl reads (<=2-way)

// W[b][k][i][j] = cheb[k][i][j] * S[b][i][j]  (+8 zero pad at end)
__global__ void k_W(const float* __restrict__ cheb, const float* __restrict__ S,
                    float* __restrict__ Wd) {
    long idx = (long)blockIdx.x * 256 + threadIdx.x;
    long tot = (long)B * K * N * N;
    if (idx >= tot) {
        if (idx < tot + 8) Wd[idx] = 0.f;
        return;
    }
    int ij = (int)(idx % (N * N));
    int k = (int)((idx / (N * N)) % K);
    int b = (int)(idx / ((long)N * N * K));
    Wd[idx] = cheb[(size_t)k * N * N + ij] * S[(size_t)b * N * N + ij];
}

// scalar-weight path: the 12 weights per i are wave-uniform -> s_load (off the
// VALU/LDS pipes). No wl staging, no per-chunk barriers. x loads: 1 dwordx3/i.
__global__ void k_gcnz_w(const float* __restrict__ x, const float* __restrict__ Wd,
                         const float* __restrict__ ThT, float* __restrict__ sg) {
    int blk = blockIdx.x;
    int b = blk / NJB;
    int j0 = (blk % NJB) * JT;
    int tid = threadIdx.x;  // 256

    __shared__ float zl[K][T][FP][JT];  // 37.4 KB -> 4 blocks/CU

    float acc[K * JT][3];
#pragma unroll
    for (int m = 0; m < K * JT; m++)
#pragma unroll
        for (int r = 0; r < 3; r++) acc[m][r] = 0.f;

    const float* xp = x + (size_t)b * N * FT + 3 * tid;
    const float* wb = Wd + (size_t)b * K * N * N + j0;

    for (int i = 0; i < N; i++) {
        float xv0 = xp[0], xv1 = xp[1], xv2 = xp[2];  // global_load_dwordx3
        float w[K * JT];
#pragma unroll
        for (int k = 0; k < K; k++)
#pragma unroll
            for (int jj = 0; jj < JT; jj++)
                w[k * JT + jj] = wb[((size_t)k * N + i) * N + jj];  // uniform -> s_load
#pragma unroll
        for (int m = 0; m < K * JT; m++) {
            acc[m][0] += w[m] * xv0;
            acc[m][1] += w[m] * xv1;
            acc[m][2] += w[m] * xv2;
        }
        xp += FT;
    }

    // acc -> zl, layout [k][t][f][jj] so stage-2 reads are float4 over jj
#pragma unroll
    for (int r = 0; r < 3; r++) {
        int e = 3 * tid + r;
        int f = e / T, t = e % T;
#pragma unroll
        for (int m = 0; m < K * JT; m++) zl[m / JT][t][f][m % JT] = acc[m][r];
    }
    __syncthreads();

    // Theta contraction + relu
#pragma unroll
    for (int r = 0; r < 3; r++) {
        int e = tid + 256 * r;  // c*T + t
        int c = e / T, t = e % T;
        float s0 = 0.f, s1 = 0.f, s2 = 0.f, s3 = 0.f;
#pragma unroll
        for (int k = 0; k < K; k++) {
            const float4* tp = (const float4*)(ThT + ((size_t)k * C + c) * F);
            const float4* zp = (const float4*)&zl[k][t][0][0];
#pragma unroll 4
            for (int fq = 0; fq < F / 4; fq++) {
                float4 tv = tp[fq];
                float4 z0 = zp[4 * fq + 0];
                float4 z1 = zp[4 * fq + 1];
                float4 z2 = zp[4 * fq + 2];
                float4 z3 = zp[4 * fq + 3];
                s0 += tv.x * z0.x + tv.y * z1.x + tv.z * z2.x + tv.w * z3.x;
                s1 += tv.x * z0.y + tv.y * z1.y + tv.z * z2.y + tv.w * z3.y;
                s2 += tv.x * z0.z + tv.y * z1.z + tv.z * z2.z + tv.w * z3.z;
                s3 += tv.x * z0.w + tv.y * z1.w + tv.z * z2.w + tv.w * z3.w;
            }
        }
        float sj[JT] = {s0, s1, s2, s3};
#pragma unroll
        for (int jj = 0; jj < JT; jj++) {
            int j = j0 + jj;
            if (j < N) sg[((size_t)b * N + j) * FT + e] = fmaxf(sj[jj], 0.f);
        }
    }
}

// fallback (workspace too small for W): previous known-good kernel
__global__ void k_gcnz(const float* __restrict__ x, const float* __restrict__ S,
                       const float* __restrict__ cheb, const float* __restrict__ Theta,
                       float* __restrict__ sg) {
    int blk = blockIdx.x;
    int b = blk / NJB;
    int j0 = (blk % NJB) * JT;
    int tid = threadIdx.x;  // 256

    __shared__ float wl[64][K * JT];  // 3 KB
    __shared__ float zl[K][JT][FT];   // 36 KB

    float acc[K][JT][3];
#pragma unroll
    for (int k = 0; k < K; k++)
#pragma unroll
        for (int jj = 0; jj < JT; jj++)
#pragma unroll
            for (int r = 0; r < 3; r++) acc[k][jj][r] = 0.f;

    const float* xb = x + (size_t)b * N * FT;

    for (int ic = 0; ic < N; ic += 64) {
        for (int l = tid; l < 64 * K * JT; l += 256) {
            int ii = l / (K * JT);
            int m = l % (K * JT);
            int k = m / JT, jj = m % JT;
            int i = ic + ii, j = j0 + jj;
            float w = 0.f;
            if (i < N && j < N)
                w = cheb[((size_t)k * N + i) * N + j] * S[((size_t)b * N + i) * N + j];
            wl[ii][m] = w;
        }
        __syncthreads();
        int imax = min(64, N - ic);
        for (int ii = 0; ii < imax; ii++) {
            float xv[3];
            const float* xr = xb + (size_t)(ic + ii) * FT;
#pragma unroll
            for (int r = 0; r < 3; r++) xv[r] = xr[tid + 256 * r];
#pragma unroll
            for (int k = 0; k < K; k++)
#pragma unroll
                for (int jj = 0; jj < JT; jj++) {
                    float w = wl[ii][k * JT + jj];
#pragma unroll
                    for (int r = 0; r < 3; r++) acc[k][jj][r] += w * xv[r];
                }
        }
        __syncthreads();
    }

#pragma unroll
    for (int k = 0; k < K; k++)
#pragma unroll
        for (int jj = 0; jj < JT; jj++)
#pragma unroll
            for (int r = 0; r < 3; r++) zl[k][jj][tid + 256 * r] = acc[k][jj][r];
    __syncthreads();

    for (int r = 0; r < 3; r++) {
        int e = tid + 256 * r;  // c*T + t
        int c = e / T;
        int t = e % T;
        float s[JT] = {0.f, 0.f, 0.f, 0.f};
        for (int k = 0; k < K; k++) {
            const float* tp = Theta + (size_t)k * F * C + c;
            const float* zp = &zl[k][0][t];
#pragma unroll 4
            for (int f = 0; f < F; f++) {
                float tv = tp[f * C];
#pragma unroll
                for (int jj = 0; jj < JT; jj++) s[jj] += zp[jj * FT + f * T] * tv;
            }
        }
#pragma unroll
        for (int jj = 0; jj < JT; jj++) {
            int j = j0 + jj;
            if (j < N) sg[((size_t)b * N + j) * FT + e] = fmaxf(s[jj], 0.f);
        }
    }
}

// ---------------- tconv + rconv + relu + LayerNorm (in-place on d_out) ----------------

constexpr int RB = 4;
constexpr int PF = 68;  // padded row: 68%8==4 -> per-t bank shift of 4, <=2-way

__global__ void k_rest(const float* __restrict__ x, const float* __restrict__ twT,
                       const float* __restrict__ tb, const float* __restrict__ rw,
                       const float* __restrict__ rb, const float* __restrict__ gamma,
                       const float* __restrict__ beta, float* __restrict__ io) {
    int blk = blockIdx.x;
    size_t bn0 = (size_t)blk * RB;
    int tid = threadIdx.x;  // 256

    __shared__ float xt[RB][T][PF];       // [t][f], 13.1 KB
    __shared__ float sgt[RB][T + 2][PF];  // [t+1][c], rows 0 & T+1 zero, 15.2 KB
    __shared__ float hl[FT];              // [ct*T+t]
    __shared__ float mus[T], rstds[T];

    for (int l = tid; l < RB * PF; l += 256) {
        int rr = l / PF, c = l % PF;
        sgt[rr][0][c] = 0.f;
        sgt[rr][T + 1][c] = 0.f;
    }
    for (int l = tid; l < RB * FT; l += 256) {
        int rr = l / FT, rem = l % FT;
        int f = rem / T, t = rem % T;  // x/sg layout: [f][t] / [c][t]
        xt[rr][t][f] = x[(bn0 + rr) * FT + rem];
        sgt[rr][t + 1][f] = io[(bn0 + rr) * FT + rem];
    }
    __syncthreads();

    for (int rr = 0; rr < RB; rr++) {
        float hreg[3];
#pragma unroll
        for (int r = 0; r < 3; r++) {
            int e = tid + 256 * r;  // ct*T + t
            int ct = e / T;
            int t = e % T;
            float acc = rb[ct] + tb[ct];
            const float4* rwp = (const float4*)(rw + (size_t)ct * F);
            const float4* xp4 = (const float4*)(&xt[rr][t][0]);
#pragma unroll 4
            for (int q = 0; q < F / 4; q++) {
                float4 w = rwp[q], v = xp4[q];
                acc += w.x * v.x + w.y * v.y + w.z * v.z + w.w * v.w;
            }
#pragma unroll
            for (int dt = 0; dt < 3; dt++) {
                const float4* twp = (const float4*)(twT + ((size_t)dt * CT + ct) * C);
                const float4* sp4 = (const float4*)(&sgt[rr][t + dt][0]);
#pragma unroll 4
                for (int q = 0; q < C / 4; q++) {
                    float4 w = twp[q], v = sp4[q];
                    acc += w.x * v.x + w.y * v.y + w.z * v.z + w.w * v.w;
                }
            }
            hreg[r] = fmaxf(acc, 0.f);
            hl[e] = hreg[r];
        }
        __syncthreads();
        if (tid < T) {
            float m = 0.f;
            for (int ct = 0; ct < CT; ct++) m += hl[ct * T + tid];
            m /= CT;
            float v = 0.f;
            for (int ct = 0; ct < CT; ct++) {
                float d = hl[ct * T + tid] - m;
                v += d * d;
            }
            v /= CT;
            mus[tid] = m;
            rstds[tid] = rsqrtf(v + LN_EPS);
        }
        __syncthreads();
        float* iop = io + (bn0 + rr) * FT;
#pragma unroll
        for (int r = 0; r < 3; r++) {
            int e = tid + 256 * r;
            int ct = e / T;
            int t = e % T;
            iop[e] = (hreg[r] - mus[t]) * rstds[t] * gamma[ct] + beta[ct];
        }
        __syncthreads();
    }
}

// ---------------- launch ----------------

extern "C" void kernel_launch(void* const* d_in, const int* in_sizes, int n_in,
                              void* d_out, int out_size, void* d_ws, size_t ws_size,
                              hipStream_t stream) {
    const float* x     = (const float*)d_in[0];
    const float* W1    = (const float*)d_in[1];
    const float* W2    = (const float*)d_in[2];
    const float* W3    = (const float*)d_in[3];
    const float* b_s   = (const float*)d_in[4];
    const float* V_s   = (const float*)d_in[5];
    const float* U1    = (const float*)d_in[6];
    const float* U2    = (const float*)d_in[7];
    const float* U3    = (const float*)d_in[8];
    const float* b_e   = (const float*)d_in[9];
    const float* V_e   = (const float*)d_in[10];
    const float* cheb  = (const float*)d_in[11];
    const float* Theta = (const float*)d_in[12];
    const float* tw    = (const float*)d_in[13];
    const float* tb    = (const float*)d_in[14];
    const float* rw    = (const float*)d_in[15];
    const float* rb    = (const float*)d_in[16];
    const float* gam   = (const float*)d_in[17];
    const float* bet   = (const float*)d_in[18];
    float* out = (float*)d_out;

    float* ws = (float*)d_ws;
    size_t off = 0;
    auto alloc = [&](size_t n) { float* p = ws + off; off += n; return p; };
    float* Sb     = alloc((size_t)B * N * N);
    float* VsT    = alloc((size_t)N * N);
    float* twT    = alloc((size_t)CT * C * 3);
    float* lhs1_e = alloc((size_t)B * T * F);
    float* lhs_e  = alloc((size_t)B * T * N);
    float* rhs_e  = alloc((size_t)B * N * T);
    float* Ebuf   = alloc((size_t)B * T * T);
    float* EW1    = alloc((size_t)B * T);
    float* xw3    = alloc((size_t)B * N * T);
    float* lhs_s  = alloc((size_t)B * N * T);
    float* rhs_s  = alloc((size_t)B * T * N);
    float* ThT    = alloc((size_t)K * F * C);

    // W = cheb (.) S : 72.4 MB — use it only if the workspace is big enough
    size_t nW = (size_t)B * K * N * N + 8;
    bool useW = ws_size >= (off + nW) * sizeof(float);
    float* Wd = ws + off;

    auto g = [](long n) { return dim3((unsigned)((n + 255) / 256)); };

    // temporal attention (k_xdots also precomputes xw3 for spatial attention)
    k_lhs1_e<<<g((long)B * T * F), 256, 0, stream>>>(x, U1, lhs1_e);
    k_xdots<<<g((long)B * N * T), 256, 0, stream>>>(x, U3, W3, rhs_e, xw3);
    k_lhs_e<<<g((long)B * T * N), 256, 0, stream>>>(lhs1_e, U2, lhs_e);
    k_tatt<<<B, 256, 0, stream>>>(lhs_e, rhs_e, b_e, V_e, Ebuf);

    // spatial attention (x_TAt folded in)
    k_EW1<<<g((long)B * T), 256, 0, stream>>>(Ebuf, W1, EW1);
    k_lhs_sf<<<B * N, 64, 0, stream>>>(x, EW1, W2, lhs_s);
    k_rhs_s2<<<g((long)B * T * N), 256, 0, stream>>>(xw3, Ebuf, rhs_s);
    k_transposeVs<<<g((long)N * N), 256, 0, stream>>>(V_s, VsT);
    k_twT<<<g((long)CT * C * 3), 256, 0, stream>>>(tw, twT);
    k_thT<<<g((long)K * F * C), 256, 0, stream>>>(Theta, ThT);
    k_sigS<<<B * NAB, 256, 0, stream>>>(lhs_s, rhs_s, b_s, VsT, Sb);
    k_softmax_S<<<g((long)B * N), 256, 0, stream>>>(Sb);

    // graph conv + Theta + relu -> sg staged in d_out
    if (useW) {
        k_W<<<g((long)B * K * N * N + 8), 256, 0, stream>>>(cheb, Sb, Wd);
        k_gcnz_w<<<B * NJB, 256, 0, stream>>>(x, Wd, ThT, out);
    } else {
        k_gcnz<<<B * NJB, 256, 0, stream>>>(x, Sb, cheb, Theta, out);
    }

    // tconv + rconv + relu + LN, in-place on d_out, RB rows per block
    k_rest<<<(B * N) / RB, 256, 0, stream>>>(x, twT, tb, rw, rb, gam, bet, out);
}

// Round 2
// 1469.611 us; speedup vs baseline: 1.1684x; 1.1206x over previous
//
#include <hip/hip_runtime.h>
#include <hip/hip_bf16.h>
#include <math.h>

constexpr int B = 64, N = 307, F = 64, T = 12, K = 3, C = 64, CT = 64;
constexpr float LN_EPS = 1e-5f;
constexpr int FT = F * T;  // 768

typedef float vf4 __attribute__((ext_vector_type(4)));

// ---------------- temporal attention ----------------

// lhs1_e[b,t,f] = sum_n x[b,n,e] * U1[n], e=(f,t) — coalesced: lanes span e
__global__ void k_lhs1_e(const float* __restrict__ x, const float* __restrict__ U1,
                         float* __restrict__ out) {
    int bb = blockIdx.x;
    int b = bb / 3;
    int e = (bb % 3) * 256 + threadIdx.x;  // e = f*T + t
    const float* xp = x + (size_t)b * N * FT + e;
    float s = 0.f;
    for (int n = 0; n < N; n++) s += xp[(size_t)n * FT] * U1[n];
    int f = e / T, t = e % T;
    out[((size_t)b * T + t) * F + f] = s;
}

// fused: rhs_e[b,n,t] = sum_f U3[f]*x[b,n,f,t];  xw3[b,n,t] = sum_f W3[f]*x[b,n,f,t]
__global__ void k_xdots(const float* __restrict__ x, const float* __restrict__ U3,
                        const float* __restrict__ W3, float* __restrict__ rhs_e,
                        float* __restrict__ xw3) {
    int idx = blockIdx.x * blockDim.x + threadIdx.x;
    if (idx >= B * N * T) return;
    int t = idx % T;
    size_t bn = idx / T;
    const float* xp = x + bn * F * T + t;
    float s1 = 0.f, s2 = 0.f;
    for (int f = 0; f < F; f++) {
        float v = xp[f * T];
        s1 += U3[f] * v;
        s2 += W3[f] * v;
    }
    rhs_e[idx] = s1;
    xw3[idx] = s2;
}

// lhs_e[b,t,n] = sum_f lhs1_e[b,t,f] * U2[f,n]
__global__ void k_lhs_e(const float* __restrict__ lhs1, const float* __restrict__ U2,
                        float* __restrict__ out) {
    int idx = blockIdx.x * blockDim.x + threadIdx.x;
    if (idx >= B * T * N) return;
    int n = idx % N;
    int bt = idx / N;
    const float* lp = lhs1 + (size_t)bt * F;
    float s = 0.f;
    for (int f = 0; f < F; f++) s += lp[f] * U2[f * N + n];
    out[idx] = s;
}

// prod/sigmoid/V_e/softmax fused per batch: E[b,u,t] softmaxed over u
__global__ void k_tatt(const float* __restrict__ lhs, const float* __restrict__ rhs,
                       const float* __restrict__ b_e, const float* __restrict__ V_e,
                       float* __restrict__ E) {
    int b = blockIdx.x;
    int tid = threadIdx.x;
    __shared__ float sig[T * T];
    __shared__ float Ev[T * T];
    __shared__ float mx[T], sm[T];
    if (tid < T * T) {
        int t = tid % T, u = tid / T;
        const float* lp = lhs + ((size_t)b * T + u) * N;
        const float* rp = rhs + (size_t)b * N * T + t;
        float s = 0.f;
        for (int n = 0; n < N; n++) s += lp[n] * rp[(size_t)n * T];
        s += b_e[u * T + t];
        sig[tid] = 1.f / (1.f + expf(-s));
    }
    __syncthreads();
    if (tid < T * T) {
        int t = tid % T, u = tid / T;
        float e = 0.f;
        for (int v = 0; v < T; v++) e += V_e[u * T + v] * sig[v * T + t];
        Ev[tid] = e;
    }
    __syncthreads();
    if (tid < T) {
        float m = -1e30f;
        for (int u = 0; u < T; u++) m = fmaxf(m, Ev[u * T + tid]);
        float s = 0.f;
        for (int u = 0; u < T; u++) s += expf(Ev[u * T + tid] - m);
        mx[tid] = m;
        sm[tid] = s;
    }
    __syncthreads();
    if (tid < T * T) {
        int t = tid % T;
        E[(size_t)b * T * T + tid] = expf(Ev[tid] - mx[t]) / sm[t];
    }
}

// EW1[b,tp] = sum_t E[b,tp,t] * W1[t]
__global__ void k_EW1(const float* __restrict__ E, const float* __restrict__ W1,
                      float* __restrict__ out) {
    int idx = blockIdx.x * blockDim.x + threadIdx.x;
    if (idx >= B * T) return;
    const float* Ep = E + (size_t)idx * T;
    float s = 0.f;
    for (int t = 0; t < T; t++) s += Ep[t] * W1[t];
    out[idx] = s;
}

// ---------------- spatial attention (x_TAt folded in algebraically) ----------------

// lhs_s[b,n,t] = sum_f (sum_tp x[b,n,f,tp]*EW1[b,tp]) * W2[f,t]
__global__ void k_lhs_sf(const float* __restrict__ x, const float* __restrict__ EW1,
                         const float* __restrict__ W2, float* __restrict__ lhs_s) {
    int bn = blockIdx.x;
    int b = bn / N;
    int tid = threadIdx.x;  // 64
    __shared__ float a[F];
    __shared__ float ew[T];
    if (tid < T) ew[tid] = EW1[(size_t)b * T + tid];
    __syncthreads();
    const float* xp = x + (size_t)bn * F * T + tid * T;  // row f = tid
    float s = 0.f;
    for (int tp = 0; tp < T; tp++) s += xp[tp] * ew[tp];
    a[tid] = s;
    __syncthreads();
    if (tid < T) {
        float s2 = 0.f;
        for (int f = 0; f < F; f++) s2 += a[f] * W2[f * T + tid];
        lhs_s[(size_t)bn * T + tid] = s2;
    }
}

// rhs_s[b,t,m] = sum_tp xw3[b,m,tp] * E[b,tp,t]
__global__ void k_rhs_s2(const float* __restrict__ xw3, const float* __restrict__ E,
                         float* __restrict__ out) {
    int idx = blockIdx.x * blockDim.x + threadIdx.x;
    if (idx >= B * T * N) return;
    int m = idx % N;
    int t = (idx / N) % T;
    int b = idx / (N * T);
    const float* xp = xw3 + ((size_t)b * N + m) * T;
    const float* Ep = E + (size_t)b * T * T + t;
    float s = 0.f;
    for (int tp = 0; tp < T; tp++) s += xp[tp] * Ep[tp * T];
    out[idx] = s;
}

// VsT[v,i] = V_s[i,v]
__global__ void k_transposeVs(const float* __restrict__ V, float* __restrict__ VT) {
    int idx = blockIdx.x * blockDim.x + threadIdx.x;
    if (idx >= N * N) return;
    int v = idx % N;
    int i = idx / N;
    VT[(size_t)v * N + i] = V[(size_t)i * N + v];
}

// twT[dt][ct][c] = tw[ct][c][dt]  (contiguous-c for float4 loads in k_rest)
__global__ void k_twT(const float* __restrict__ tw, float* __restrict__ twT) {
    int idx = blockIdx.x * blockDim.x + threadIdx.x;
    if (idx >= CT * C * 3) return;
    int dt = idx % 3;
    int c = (idx / 3) % C;
    int ct = idx / (3 * C);
    twT[((size_t)dt * CT + ct) * C + c] = tw[idx];
}

// ThT[k][c][f] = Theta[k][f][c]  (contiguous-f for float4 loads in gcnz stage-2)
__global__ void k_thT(const float* __restrict__ Th, float* __restrict__ ThT) {
    int idx = blockIdx.x * blockDim.x + threadIdx.x;
    if (idx >= K * F * C) return;
    int c = idx % C;
    int f = (idx / C) % F;
    int k = idx / (C * F);
    ThT[((size_t)k * C + c) * F + f] = Th[idx];
}

// fused sigmoid + V_s projection, AT=4 rows per block for VsT reuse
constexpr int AT = 4;
constexpr int NAB = (N + AT - 1) / AT;  // 77

__global__ void k_sigS(const float* __restrict__ lhs_s, const float* __restrict__ rhs_s,
                       const float* __restrict__ b_s, const float* __restrict__ VsT,
                       float* __restrict__ S) {
    int blk = blockIdx.x;
    int b = blk / NAB;
    int a0 = (blk % NAB) * AT;
    int tid = threadIdx.x;  // 256
    __shared__ float lrow[AT][T];
    __shared__ float sig4[AT][N];
    if (tid < AT * T) {
        int a = tid / T, t = tid % T;
        lrow[a][t] = (a0 + a < N) ? lhs_s[((size_t)b * N + a0 + a) * T + t] : 0.f;
    }
    __syncthreads();
    for (int v = tid; v < N; v += 256) {
        float rv[T];
        for (int t = 0; t < T; t++) rv[t] = rhs_s[((size_t)b * T + t) * N + v];
        for (int a = 0; a < AT; a++) {
            if (a0 + a >= N) break;
            float s = 0.f;
            for (int t = 0; t < T; t++) s += lrow[a][t] * rv[t];
            s += b_s[(size_t)(a0 + a) * N + v];
            sig4[a][v] = 1.f / (1.f + expf(-s));
        }
    }
    __syncthreads();
    for (int i = tid; i < N; i += 256) {
        float s[AT] = {0.f, 0.f, 0.f, 0.f};
        for (int v = 0; v < N; v++) {
            float vt = VsT[(size_t)v * N + i];
            for (int a = 0; a < AT; a++) s[a] += sig4[a][v] * vt;
        }
        for (int a = 0; a < AT; a++)
            if (a0 + a < N) S[((size_t)b * N + a0 + a) * N + i] = s[a];
    }
}

// softmax over a (axis 1) for each (b, i) — lanes span consecutive i => coalesced
__global__ void k_softmax_S(float* __restrict__ S) {
    int idx = blockIdx.x * blockDim.x + threadIdx.x;
    if (idx >= B * N) return;
    int b = idx / N;
    int i = idx % N;
    float* p = S + (size_t)b * N * N + i;
    float m = -1e30f;
    for (int a = 0; a < N; a++) m = fmaxf(m, p[(size_t)a * N]);
    float s = 0.f;
    for (int a = 0; a < N; a++) s += expf(p[(size_t)a * N] - m);
    float inv = 1.f / s;
    for (int a = 0; a < N; a++) p[(size_t)a * N] = expf(p[(size_t)a * N] - m) * inv;
}

// ---------------- chebyshev graph conv + Theta + relu -> sg (in d_out) ----------------

constexpr int JT = 4;
constexpr int NJB = (N + JT - 1) / JT;  // 77

// Wp[((b*NJB+jb)*N + i)*12 + k*4+jj] = cheb[k,i,jb*4+jj] * S[b,i,jb*4+jj]  (0 if j>=N)
// padded per-jblock layout: each i is 48B of wave-uniform weights -> s_load stream
__global__ void k_Wp(const float* __restrict__ cheb, const float* __restrict__ S,
                     float* __restrict__ Wp) {
    long idx = (long)blockIdx.x * 256 + threadIdx.x;
    long tot = (long)B * NJB * N * 12;
    if (idx >= tot) return;
    int q = (int)(idx % 12);
    int i = (int)((idx / 12) % N);
    int jb = (int)((idx / (12L * N)) % NJB);
    int b = (int)(idx / (12L * N * NJB));
    int k = q >> 2, jj = q & 3;
    int j = jb * 4 + jj;
    float w = 0.f;
    if (j < N) w = cheb[((size_t)k * N + i) * N + j] * S[((size_t)b * N + i) * N + j];
    Wp[idx] = w;
}

// stage-1: depth-1 software pipeline, uniform (scalar) weight loads, dwordx3 x loads
// stage-2: c-blocked (CP=4) Theta contraction — z b128 reused across 4 c's
__global__ __launch_bounds__(256, 4) void k_gcnz_p(const float* __restrict__ x,
                                                   const float* __restrict__ Wp,
                                                   const float* __restrict__ ThT,
                                                   float* __restrict__ sg) {
    int blk = blockIdx.x;
    int b = blk / NJB;
    int jb = blk % NJB;
    int j0 = jb * JT;
    int tid = threadIdx.x;  // 256

    __shared__ float zl[K][F][T][JT];  // 36,864 B -> 4 blocks/CU

    float acc[K * JT][3];
#pragma unroll
    for (int m = 0; m < K * JT; m++)
#pragma unroll
        for (int r = 0; r < 3; r++) acc[m][r] = 0.f;

    const float* xp = x + (size_t)b * N * FT + 3 * tid;
    const float* wb = Wp + ((size_t)b * NJB + jb) * N * 12;

    // prologue loads (i = 0)
    float wc[12];
    {
        const vf4* wp4 = (const vf4*)wb;
        vf4 a = wp4[0], b4 = wp4[1], c4 = wp4[2];
#pragma unroll
        for (int q = 0; q < 4; q++) {
            wc[q] = a[q];
            wc[4 + q] = b4[q];
            wc[8 + q] = c4[q];
        }
    }
    float x0 = xp[0], x1 = xp[1], x2 = xp[2];

    for (int i = 0; i < N - 1; i++) {
        // prefetch i+1 (uniform weights -> scalar cache; x -> dwordx3)
        float wn[12];
        {
            const vf4* wp4 = (const vf4*)(wb + (size_t)(i + 1) * 12);
            vf4 a = wp4[0], b4 = wp4[1], c4 = wp4[2];
#pragma unroll
            for (int q = 0; q < 4; q++) {
                wn[q] = a[q];
                wn[4 + q] = b4[q];
                wn[8 + q] = c4[q];
            }
        }
        float nx0 = xp[FT], nx1 = xp[FT + 1], nx2 = xp[FT + 2];
#pragma unroll
        for (int m = 0; m < K * JT; m++) {
            acc[m][0] += wc[m] * x0;
            acc[m][1] += wc[m] * x1;
            acc[m][2] += wc[m] * x2;
        }
#pragma unroll
        for (int m = 0; m < K * JT; m++) wc[m] = wn[m];
        x0 = nx0;
        x1 = nx1;
        x2 = nx2;
        xp += FT;
    }
#pragma unroll
    for (int m = 0; m < K * JT; m++) {
        acc[m][0] += wc[m] * x0;
        acc[m][1] += wc[m] * x1;
        acc[m][2] += wc[m] * x2;
    }

    // acc -> zl[k][f][t][jj]
#pragma unroll
    for (int r = 0; r < 3; r++) {
        int e = 3 * tid + r;
        int f = e / T, t = e % T;
#pragma unroll
        for (int m = 0; m < K * JT; m++) zl[m >> 2][f][t][m & 3] = acc[m][r];
    }
    __syncthreads();

    // Theta contraction, c-blocked: thread = (t, c-group of 4), 192 active
    if (tid < 192) {
        int t = tid % T;
        int c0 = (tid / T) * 4;
        float s[4][4];  // [cc][jj]
#pragma unroll
        for (int cc = 0; cc < 4; cc++)
#pragma unroll
            for (int jj = 0; jj < 4; jj++) s[cc][jj] = 0.f;

#pragma unroll
        for (int k = 0; k < K; k++) {
            const vf4* zpk = (const vf4*)&zl[k][0][t][0];  // stride per f: 12 vf4
            const vf4* tp0 = (const vf4*)(ThT + ((size_t)k * C + c0 + 0) * F);
            const vf4* tp1 = (const vf4*)(ThT + ((size_t)k * C + c0 + 1) * F);
            const vf4* tp2 = (const vf4*)(ThT + ((size_t)k * C + c0 + 2) * F);
            const vf4* tp3 = (const vf4*)(ThT + ((size_t)k * C + c0 + 3) * F);
#pragma unroll 4
            for (int fq = 0; fq < F / 4; fq++) {
                vf4 z0 = zpk[(4 * fq + 0) * 12];
                vf4 z1 = zpk[(4 * fq + 1) * 12];
                vf4 z2 = zpk[(4 * fq + 2) * 12];
                vf4 z3 = zpk[(4 * fq + 3) * 12];
                vf4 th[4];
                th[0] = tp0[fq];
                th[1] = tp1[fq];
                th[2] = tp2[fq];
                th[3] = tp3[fq];
#pragma unroll
                for (int cc = 0; cc < 4; cc++) {
#pragma unroll
                    for (int jj = 0; jj < 4; jj++)
                        s[cc][jj] += th[cc][0] * z0[jj] + th[cc][1] * z1[jj] +
                                     th[cc][2] * z2[jj] + th[cc][3] * z3[jj];
                }
            }
        }
#pragma unroll
        for (int jj = 0; jj < 4; jj++) {
            int j = j0 + jj;
            if (j < N) {
                float* op = sg + ((size_t)b * N + j) * FT + (size_t)c0 * T + t;
                op[0 * T] = fmaxf(s[0][jj], 0.f);
                op[1 * T] = fmaxf(s[1][jj], 0.f);
                op[2 * T] = fmaxf(s[2][jj], 0.f);
                op[3 * T] = fmaxf(s[3][jj], 0.f);
            }
        }
    }
}

// fallback (workspace too small for Wp): original known-good kernel
__global__ void k_gcnz(const float* __restrict__ x, const float* __restrict__ S,
                       const float* __restrict__ cheb, const float* __restrict__ Theta,
                       float* __restrict__ sg) {
    int blk = blockIdx.x;
    int b = blk / NJB;
    int j0 = (blk % NJB) * JT;
    int tid = threadIdx.x;  // 256

    __shared__ float wl[64][K * JT];  // 3 KB
    __shared__ float zl[K][JT][FT];   // 36 KB

    float acc[K][JT][3];
#pragma unroll
    for (int k = 0; k < K; k++)
#pragma unroll
        for (int jj = 0; jj < JT; jj++)
#pragma unroll
            for (int r = 0; r < 3; r++) acc[k][jj][r] = 0.f;

    const float* xb = x + (size_t)b * N * FT;

    for (int ic = 0; ic < N; ic += 64) {
        for (int l = tid; l < 64 * K * JT; l += 256) {
            int ii = l / (K * JT);
            int m = l % (K * JT);
            int k = m / JT, jj = m % JT;
            int i = ic + ii, j = j0 + jj;
            float w = 0.f;
            if (i < N && j < N)
                w = cheb[((size_t)k * N + i) * N + j] * S[((size_t)b * N + i) * N + j];
            wl[ii][m] = w;
        }
        __syncthreads();
        int imax = min(64, N - ic);
        for (int ii = 0; ii < imax; ii++) {
            float xv[3];
            const float* xr = xb + (size_t)(ic + ii) * FT;
#pragma unroll
            for (int r = 0; r < 3; r++) xv[r] = xr[tid + 256 * r];
#pragma unroll
            for (int k = 0; k < K; k++)
#pragma unroll
                for (int jj = 0; jj < JT; jj++) {
                    float w = wl[ii][k * JT + jj];
#pragma unroll
                    for (int r = 0; r < 3; r++) acc[k][jj][r] += w * xv[r];
                }
        }
        __syncthreads();
    }

#pragma unroll
    for (int k = 0; k < K; k++)
#pragma unroll
        for (int jj = 0; jj < JT; jj++)
#pragma unroll
            for (int r = 0; r < 3; r++) zl[k][jj][tid + 256 * r] = acc[k][jj][r];
    __syncthreads();

    for (int r = 0; r < 3; r++) {
        int e = tid + 256 * r;  // c*T + t
        int c = e / T;
        int t = e % T;
        float s[JT] = {0.f, 0.f, 0.f, 0.f};
        for (int k = 0; k < K; k++) {
            const float* tp = Theta + (size_t)k * F * C + c;
            const float* zp = &zl[k][0][t];
#pragma unroll 4
            for (int f = 0; f < F; f++) {
                float tv = tp[f * C];
#pragma unroll
                for (int jj = 0; jj < JT; jj++) s[jj] += zp[jj * FT + f * T] * tv;
            }
        }
#pragma unroll
        for (int jj = 0; jj < JT; jj++) {
            int j = j0 + jj;
            if (j < N) sg[((size_t)b * N + j) * FT + e] = fmaxf(s[jj], 0.f);
        }
    }
}

// ---------------- tconv + rconv + relu + LayerNorm (in-place on d_out) ----------------

constexpr int RB = 4;
constexpr int PF = 68;  // padded row: 68%8==4 -> per-t bank shift of 4, <=2-way

__global__ void k_rest(const float* __restrict__ x, const float* __restrict__ twT,
                       const float* __restrict__ tb, const float* __restrict__ rw,
                       const float* __restrict__ rb, const float* __restrict__ gamma,
                       const float* __restrict__ beta, float* __restrict__ io) {
    int blk = blockIdx.x;
    size_t bn0 = (size_t)blk * RB;
    int tid = threadIdx.x;  // 256

    __shared__ float xt[RB][T][PF];       // [t][f], 13.1 KB
    __shared__ float sgt[RB][T + 2][PF];  // [t+1][c], rows 0 & T+1 zero, 15.2 KB
    __shared__ float hl[FT];              // [ct*T+t]
    __shared__ float mus[T], rstds[T];

    for (int l = tid; l < RB * PF; l += 256) {
        int rr = l / PF, c = l % PF;
        sgt[rr][0][c] = 0.f;
        sgt[rr][T + 1][c] = 0.f;
    }
    for (int l = tid; l < RB * FT; l += 256) {
        int rr = l / FT, rem = l % FT;
        int f = rem / T, t = rem % T;  // x/sg layout: [f][t] / [c][t]
        xt[rr][t][f] = x[(bn0 + rr) * FT + rem];
        sgt[rr][t + 1][f] = io[(bn0 + rr) * FT + rem];
    }
    __syncthreads();

    for (int rr = 0; rr < RB; rr++) {
        float hreg[3];
#pragma unroll
        for (int r = 0; r < 3; r++) {
            int e = tid + 256 * r;  // ct*T + t
            int ct = e / T;
            int t = e % T;
            float acc = rb[ct] + tb[ct];
            const float4* rwp = (const float4*)(rw + (size_t)ct * F);
            const float4* xp4 = (const float4*)(&xt[rr][t][0]);
#pragma unroll 4
            for (int q = 0; q < F / 4; q++) {
                float4 w = rwp[q], v = xp4[q];
                acc += w.x * v.x + w.y * v.y + w.z * v.z + w.w * v.w;
            }
#pragma unroll
            for (int dt = 0; dt < 3; dt++) {
                const float4* twp = (const float4*)(twT + ((size_t)dt * CT + ct) * C);
                const float4* sp4 = (const float4*)(&sgt[rr][t + dt][0]);
#pragma unroll 4
                for (int q = 0; q < C / 4; q++) {
                    float4 w = twp[q], v = sp4[q];
                    acc += w.x * v.x + w.y * v.y + w.z * v.z + w.w * v.w;
                }
            }
            hreg[r] = fmaxf(acc, 0.f);
            hl[e] = hreg[r];
        }
        __syncthreads();
        if (tid < T) {
            float m = 0.f;
            for (int ct = 0; ct < CT; ct++) m += hl[ct * T + tid];
            m /= CT;
            float v = 0.f;
            for (int ct = 0; ct < CT; ct++) {
                float d = hl[ct * T + tid] - m;
                v += d * d;
            }
            v /= CT;
            mus[tid] = m;
            rstds[tid] = rsqrtf(v + LN_EPS);
        }
        __syncthreads();
        float* iop = io + (bn0 + rr) * FT;
#pragma unroll
        for (int r = 0; r < 3; r++) {
            int e = tid + 256 * r;
            int ct = e / T;
            int t = e % T;
            iop[e] = (hreg[r] - mus[t]) * rstds[t] * gamma[ct] + beta[ct];
        }
        __syncthreads();
    }
}

// ---------------- launch ----------------

extern "C" void kernel_launch(void* const* d_in, const int* in_sizes, int n_in,
                              void* d_out, int out_size, void* d_ws, size_t ws_size,
                              hipStream_t stream) {
    const float* x     = (const float*)d_in[0];
    const float* W1    = (const float*)d_in[1];
    const float* W2    = (const float*)d_in[2];
    const float* W3    = (const float*)d_in[3];
    const float* b_s   = (const float*)d_in[4];
    const float* V_s   = (const float*)d_in[5];
    const float* U1    = (const float*)d_in[6];
    const float* U2    = (const float*)d_in[7];
    const float* U3    = (const float*)d_in[8];
    const float* b_e   = (const float*)d_in[9];
    const float* V_e   = (const float*)d_in[10];
    const float* cheb  = (const float*)d_in[11];
    const float* Theta = (const float*)d_in[12];
    const float* tw    = (const float*)d_in[13];
    const float* tb    = (const float*)d_in[14];
    const float* rw    = (const float*)d_in[15];
    const float* rb    = (const float*)d_in[16];
    const float* gam   = (const float*)d_in[17];
    const float* bet   = (const float*)d_in[18];
    float* out = (float*)d_out;

    float* ws = (float*)d_ws;
    size_t off = 0;
    auto alloc = [&](size_t n) { float* p = ws + off; off += n; return p; };
    float* Sb     = alloc((size_t)B * N * N);
    float* VsT    = alloc((size_t)N * N);
    float* twT    = alloc((size_t)CT * C * 3);
    float* lhs1_e = alloc((size_t)B * T * F);
    float* lhs_e  = alloc((size_t)B * T * N);
    float* rhs_e  = alloc((size_t)B * N * T);
    float* Ebuf   = alloc((size_t)B * T * T);
    float* EW1    = alloc((size_t)B * T);
    float* xw3    = alloc((size_t)B * N * T);
    float* lhs_s  = alloc((size_t)B * N * T);
    float* rhs_s  = alloc((size_t)B * T * N);
    float* ThT    = alloc((size_t)K * F * C);

    // Wp = padded per-jblock cheb (.) S : 72.6 MB, 16B-aligned
    off = (off + 3) & ~(size_t)3;
    size_t nWp = (size_t)B * NJB * N * 12;
    bool useWp = ws_size >= (off + nWp) * sizeof(float);
    float* Wp = ws + off;

    auto g = [](long n) { return dim3((unsigned)((n + 255) / 256)); };

    // temporal attention (k_xdots also precomputes xw3 for spatial attention)
    k_lhs1_e<<<dim3(B * 3), 256, 0, stream>>>(x, U1, lhs1_e);
    k_xdots<<<g((long)B * N * T), 256, 0, stream>>>(x, U3, W3, rhs_e, xw3);
    k_lhs_e<<<g((long)B * T * N), 256, 0, stream>>>(lhs1_e, U2, lhs_e);
    k_tatt<<<B, 256, 0, stream>>>(lhs_e, rhs_e, b_e, V_e, Ebuf);

    // spatial attention (x_TAt folded in)
    k_EW1<<<g((long)B * T), 256, 0, stream>>>(Ebuf, W1, EW1);
    k_lhs_sf<<<B * N, 64, 0, stream>>>(x, EW1, W2, lhs_s);
    k_rhs_s2<<<g((long)B * T * N), 256, 0, stream>>>(xw3, Ebuf, rhs_s);
    k_transposeVs<<<g((long)N * N), 256, 0, stream>>>(V_s, VsT);
    k_twT<<<g((long)CT * C * 3), 256, 0, stream>>>(tw, twT);
    k_thT<<<g((long)K * F * C), 256, 0, stream>>>(Theta, ThT);
    k_sigS<<<B * NAB, 256, 0, stream>>>(lhs_s, rhs_s, b_s, VsT, Sb);
    k_softmax_S<<<g((long)B * N), 256, 0, stream>>>(Sb);

    // graph conv + Theta + relu -> sg staged in d_out
    if (useWp) {
        k_Wp<<<g((long)B * NJB * N * 12), 256, 0, stream>>>(cheb, Sb, Wp);
        k_gcnz_p<<<B * NJB, 256, 0, stream>>>(x, Wp, ThT, out);
    } else {
        k_gcnz<<<B * NJB, 256, 0, stream>>>(x, Sb, cheb, Theta, out);
    }

    // tconv + rconv + relu + LN, in-place on d_out, RB rows per block
    k_rest<<<(B * N) / RB, 256, 0, stream>>>(x, twT, tb, rw, rb, gam, bet, out);
}

// Round 4
// 1225.075 us; speedup vs baseline: 1.4017x; 1.1996x over previous
//
#include <hip/hip_runtime.h>
#include <hip/hip_bf16.h>
#include <math.h>

constexpr int B = 64, N = 307, F = 64, T = 12, K = 3, C = 64, CT = 64;
constexpr float LN_EPS = 1e-5f;
constexpr int FT = F * T;  // 768

typedef float vf4 __attribute__((ext_vector_type(4)));

// ---------------- temporal attention ----------------

// lhs1_e[b,t,f] = sum_n x[b,n,e] * U1[n], e=(f,t) — coalesced: lanes span e
__global__ void k_lhs1_e(const float* __restrict__ x, const float* __restrict__ U1,
                         float* __restrict__ out) {
    int bb = blockIdx.x;
    int b = bb / 3;
    int e = (bb % 3) * 256 + threadIdx.x;  // e = f*T + t
    const float* xp = x + (size_t)b * N * FT + e;
    float s = 0.f;
    for (int n = 0; n < N; n++) s += xp[(size_t)n * FT] * U1[n];
    int f = e / T, t = e % T;
    out[((size_t)b * T + t) * F + f] = s;
}

// fused: rhs_e[b,n,t] = sum_f U3[f]*x[b,n,f,t];  xw3[b,n,t] = sum_f W3[f]*x[b,n,f,t]
__global__ void k_xdots(const float* __restrict__ x, const float* __restrict__ U3,
                        const float* __restrict__ W3, float* __restrict__ rhs_e,
                        float* __restrict__ xw3) {
    int idx = blockIdx.x * blockDim.x + threadIdx.x;
    if (idx >= B * N * T) return;
    int t = idx % T;
    size_t bn = idx / T;
    const float* xp = x + bn * F * T + t;
    float s1 = 0.f, s2 = 0.f;
    for (int f = 0; f < F; f++) {
        float v = xp[f * T];
        s1 += U3[f] * v;
        s2 += W3[f] * v;
    }
    rhs_e[idx] = s1;
    xw3[idx] = s2;
}

// lhs_e[b,t,n] = sum_f lhs1_e[b,t,f] * U2[f,n]
__global__ void k_lhs_e(const float* __restrict__ lhs1, const float* __restrict__ U2,
                        float* __restrict__ out) {
    int idx = blockIdx.x * blockDim.x + threadIdx.x;
    if (idx >= B * T * N) return;
    int n = idx % N;
    int bt = idx / N;
    const float* lp = lhs1 + (size_t)bt * F;
    float s = 0.f;
    for (int f = 0; f < F; f++) s += lp[f] * U2[f * N + n];
    out[idx] = s;
}

// prod/sigmoid/V_e/softmax fused per batch: E[b,u,t] softmaxed over u
// v3: lhs/rhs staged+transposed in LDS -> float4 dots (was 307-iter global loop)
__global__ void k_tatt(const float* __restrict__ lhs, const float* __restrict__ rhs,
                       const float* __restrict__ b_e, const float* __restrict__ V_e,
                       float* __restrict__ E) {
    int b = blockIdx.x;
    int tid = threadIdx.x;  // 256
    __shared__ float ll[T][N + 1];   // [u][n]
    __shared__ float rr_[T][N + 1];  // [t][n]
    __shared__ float sig[T * T];
    __shared__ float Ev[T * T];
    __shared__ float mx[T], sm[T];
    for (int l = tid; l < T * N; l += 256) ll[l / N][l % N] = lhs[(size_t)b * T * N + l];
    for (int l = tid; l < N * T; l += 256) rr_[l % T][l / T] = rhs[(size_t)b * N * T + l];
    __syncthreads();
    if (tid < T * T) {
        int t = tid % T, u = tid / T;
        const vf4* lp4 = (const vf4*)&ll[u][0];
        const vf4* rp4 = (const vf4*)&rr_[t][0];
        float s = 0.f;
#pragma unroll 4
        for (int q = 0; q < 76; q++) {
            vf4 a = lp4[q], c = rp4[q];
            s += a[0] * c[0] + a[1] * c[1] + a[2] * c[2] + a[3] * c[3];
        }
        for (int n = 304; n < N; n++) s += ll[u][n] * rr_[t][n];
        s += b_e[u * T + t];
        sig[tid] = 1.f / (1.f + expf(-s));
    }
    __syncthreads();
    if (tid < T * T) {
        int t = tid % T, u = tid / T;
        float e = 0.f;
        for (int v = 0; v < T; v++) e += V_e[u * T + v] * sig[v * T + t];
        Ev[tid] = e;
    }
    __syncthreads();
    if (tid < T) {
        float m = -1e30f;
        for (int u = 0; u < T; u++) m = fmaxf(m, Ev[u * T + tid]);
        float s = 0.f;
        for (int u = 0; u < T; u++) s += expf(Ev[u * T + tid] - m);
        mx[tid] = m;
        sm[tid] = s;
    }
    __syncthreads();
    if (tid < T * T) {
        int t = tid % T;
        E[(size_t)b * T * T + tid] = expf(Ev[tid] - mx[t]) / sm[t];
    }
}

// EW1[b,tp] = sum_t E[b,tp,t] * W1[t]
__global__ void k_EW1(const float* __restrict__ E, const float* __restrict__ W1,
                      float* __restrict__ out) {
    int idx = blockIdx.x * blockDim.x + threadIdx.x;
    if (idx >= B * T) return;
    const float* Ep = E + (size_t)idx * T;
    float s = 0.f;
    for (int t = 0; t < T; t++) s += Ep[t] * W1[t];
    out[idx] = s;
}

// ---------------- spatial attention (x_TAt folded in algebraically) ----------------

// lhs_s[b,n,t] = sum_f (sum_tp x[b,n,f,tp]*EW1[b,tp]) * W2[f,t]
__global__ void k_lhs_sf(const float* __restrict__ x, const float* __restrict__ EW1,
                         const float* __restrict__ W2, float* __restrict__ lhs_s) {
    int bn = blockIdx.x;
    int b = bn / N;
    int tid = threadIdx.x;  // 64
    __shared__ float a[F];
    __shared__ float ew[T];
    if (tid < T) ew[tid] = EW1[(size_t)b * T + tid];
    __syncthreads();
    const float* xp = x + (size_t)bn * F * T + tid * T;  // row f = tid
    float s = 0.f;
    for (int tp = 0; tp < T; tp++) s += xp[tp] * ew[tp];
    a[tid] = s;
    __syncthreads();
    if (tid < T) {
        float s2 = 0.f;
        for (int f = 0; f < F; f++) s2 += a[f] * W2[f * T + tid];
        lhs_s[(size_t)bn * T + tid] = s2;
    }
}

// rhs_s[b,t,m] = sum_tp xw3[b,m,tp] * E[b,tp,t]
__global__ void k_rhs_s2(const float* __restrict__ xw3, const float* __restrict__ E,
                         float* __restrict__ out) {
    int idx = blockIdx.x * blockDim.x + threadIdx.x;
    if (idx >= B * T * N) return;
    int m = idx % N;
    int t = (idx / N) % T;
    int b = idx / (N * T);
    const float* xp = xw3 + ((size_t)b * N + m) * T;
    const float* Ep = E + (size_t)b * T * T + t;
    float s = 0.f;
    for (int tp = 0; tp < T; tp++) s += xp[tp] * Ep[tp * T];
    out[idx] = s;
}

// VsT[v,i] = V_s[i,v]
__global__ void k_transposeVs(const float* __restrict__ V, float* __restrict__ VT) {
    int idx = blockIdx.x * blockDim.x + threadIdx.x;
    if (idx >= N * N) return;
    int v = idx % N;
    int i = idx / N;
    VT[(size_t)v * N + i] = V[(size_t)i * N + v];
}

// twT[dt][ct][c] = tw[ct][c][dt]  (contiguous-c for float4 loads in k_rest)
__global__ void k_twT(const float* __restrict__ tw, float* __restrict__ twT) {
    int idx = blockIdx.x * blockDim.x + threadIdx.x;
    if (idx >= CT * C * 3) return;
    int dt = idx % 3;
    int c = (idx / 3) % C;
    int ct = idx / (3 * C);
    twT[((size_t)dt * CT + ct) * C + c] = tw[idx];
}

// ThT[k][c][f] = Theta[k][f][c]  (contiguous-f for float4 loads in gcnz stage-2)
__global__ void k_thT(const float* __restrict__ Th, float* __restrict__ ThT) {
    int idx = blockIdx.x * blockDim.x + threadIdx.x;
    if (idx >= K * F * C) return;
    int c = idx % C;
    int f = (idx / C) % F;
    int k = idx / (C * F);
    ThT[((size_t)k * C + c) * F + f] = Th[idx];
}

// fused sigmoid + V_s projection, AT=4 rows per block for VsT reuse
constexpr int AT = 4;
constexpr int NAB = (N + AT - 1) / AT;  // 77

__global__ void k_sigS(const float* __restrict__ lhs_s, const float* __restrict__ rhs_s,
                       const float* __restrict__ b_s, const float* __restrict__ VsT,
                       float* __restrict__ S) {
    int blk = blockIdx.x;
    int b = blk / NAB;
    int a0 = (blk % NAB) * AT;
    int tid = threadIdx.x;  // 256
    __shared__ float lrow[AT][T];
    __shared__ float sig4[AT][N];
    if (tid < AT * T) {
        int a = tid / T, t = tid % T;
        lrow[a][t] = (a0 + a < N) ? lhs_s[((size_t)b * N + a0 + a) * T + t] : 0.f;
    }
    __syncthreads();
    for (int v = tid; v < N; v += 256) {
        float rv[T];
        for (int t = 0; t < T; t++) rv[t] = rhs_s[((size_t)b * T + t) * N + v];
        for (int a = 0; a < AT; a++) {
            if (a0 + a >= N) break;
            float s = 0.f;
            for (int t = 0; t < T; t++) s += lrow[a][t] * rv[t];
            s += b_s[(size_t)(a0 + a) * N + v];
            sig4[a][v] = 1.f / (1.f + expf(-s));
        }
    }
    __syncthreads();
    for (int i = tid; i < N; i += 256) {
        float s[AT] = {0.f, 0.f, 0.f, 0.f};
        for (int v = 0; v < N; v++) {
            float vt = VsT[(size_t)v * N + i];
            for (int a = 0; a < AT; a++) s[a] += sig4[a][v] * vt;
        }
        for (int a = 0; a < AT; a++)
            if (a0 + a < N) S[((size_t)b * N + a0 + a) * N + i] = s[a];
    }
}

// softmax over a (axis 1) for each (b, i) — lanes span consecutive i => coalesced
__global__ void k_softmax_S(float* __restrict__ S) {
    int idx = blockIdx.x * blockDim.x + threadIdx.x;
    if (idx >= B * N) return;
    int b = idx / N;
    int i = idx % N;
    float* p = S + (size_t)b * N * N + i;
    float m = -1e30f;
    for (int a = 0; a < N; a++) m = fmaxf(m, p[(size_t)a * N]);
    float s = 0.f;
    for (int a = 0; a < N; a++) s += expf(p[(size_t)a * N] - m);
    float inv = 1.f / s;
    for (int a = 0; a < N; a++) p[(size_t)a * N] = expf(p[(size_t)a * N] - m) * inv;
}

// ---------------- chebyshev graph conv + Theta + relu -> sg (in d_out) ----------------

constexpr int JT = 4;
constexpr int NJB = (N + JT - 1) / JT;  // 77

// Wp[((b*NJB+jb)*N + i)*12 + k*4+jj] = cheb[k,i,jb*4+jj] * S[b,i,jb*4+jj]  (0 if j>=N)
__global__ void k_Wp(const float* __restrict__ cheb, const float* __restrict__ S,
                     float* __restrict__ Wp) {
    long idx = (long)blockIdx.x * 256 + threadIdx.x;
    long tot = (long)B * NJB * N * 12;
    if (idx >= tot) return;
    int q = (int)(idx % 12);
    int i = (int)((idx / 12) % N);
    int jb = (int)((idx / (12L * N)) % NJB);
    int b = (int)(idx / (12L * N * NJB));
    int k = q >> 2, jj = q & 3;
    int j = jb * 4 + jj;
    float w = 0.f;
    if (j < N) w = cheb[((size_t)k * N + i) * N + j] * S[((size_t)b * N + i) * N + j];
    Wp[idx] = w;
}

// stage-1: depth-3 rotated software pipeline (108 FMAs between issue and wait)
// stage-2: c-blocked (CP=4) Theta contraction — z b128 reused across 4 c's
__global__ __launch_bounds__(256, 4) void k_gcnz_p(const float* __restrict__ x,
                                                   const float* __restrict__ Wp,
                                                   const float* __restrict__ ThT,
                                                   float* __restrict__ sg) {
    int blk = blockIdx.x;
    int b = blk / NJB;
    int jb = blk % NJB;
    int j0 = jb * JT;
    int tid = threadIdx.x;  // 256

    __shared__ float zl[K][F][T][JT];  // 36,864 B

    float acc[K * JT][3];
#pragma unroll
    for (int m = 0; m < K * JT; m++)
#pragma unroll
        for (int r = 0; r < 3; r++) acc[m][r] = 0.f;

    const float* xp = x + (size_t)b * N * FT + 3 * tid;
    const float* wb = Wp + ((size_t)b * NJB + jb) * N * 12;

    float w0[12], w1[12], w2[12];
    float x0[3], x1[3], x2[3];

    auto LD = [&](float* wreg, float* xreg, int i) {
        const vf4* p = (const vf4*)(wb + (size_t)i * 12);
        vf4 a = p[0], b4 = p[1], c4 = p[2];
#pragma unroll
        for (int q = 0; q < 4; q++) {
            wreg[q] = a[q];
            wreg[4 + q] = b4[q];
            wreg[8 + q] = c4[q];
        }
        const float* xq = xp + (size_t)i * FT;
        xreg[0] = xq[0];
        xreg[1] = xq[1];
        xreg[2] = xq[2];
    };
    auto FMA = [&](const float* wreg, const float* xreg) {
#pragma unroll
        for (int m = 0; m < K * JT; m++) {
            acc[m][0] += wreg[m] * xreg[0];
            acc[m][1] += wreg[m] * xreg[1];
            acc[m][2] += wreg[m] * xreg[2];
        }
    };

    LD(w0, x0, 0);
    LD(w1, x1, 1);
    LD(w2, x2, 2);
    int i = 0;
    for (; i + 5 < N; i += 3) {
        float a0[12], a1[12], a2[12], y0[3], y1[3], y2[3];
        LD(a0, y0, i + 3);
        LD(a1, y1, i + 4);
        LD(a2, y2, i + 5);
        FMA(w0, x0);
        FMA(w1, x1);
        FMA(w2, x2);
#pragma unroll
        for (int m = 0; m < 12; m++) {
            w0[m] = a0[m];
            w1[m] = a1[m];
            w2[m] = a2[m];
        }
#pragma unroll
        for (int r = 0; r < 3; r++) {
            x0[r] = y0[r];
            x1[r] = y1[r];
            x2[r] = y2[r];
        }
    }
    // slots hold i, i+1, i+2
    FMA(w0, x0);
    FMA(w1, x1);
    FMA(w2, x2);
    for (i += 3; i < N; i++) {
        LD(w0, x0, i);
        FMA(w0, x0);
    }

    // acc -> zl[k][f][t][jj]
#pragma unroll
    for (int r = 0; r < 3; r++) {
        int e = 3 * tid + r;
        int f = e / T, t = e % T;
#pragma unroll
        for (int m = 0; m < K * JT; m++) zl[m >> 2][f][t][m & 3] = acc[m][r];
    }
    __syncthreads();

    // Theta contraction, c-blocked: thread = (t, c-group of 4), 192 active
    if (tid < 192) {
        int t = tid % T;
        int c0 = (tid / T) * 4;
        float s[4][4];  // [cc][jj]
#pragma unroll
        for (int cc = 0; cc < 4; cc++)
#pragma unroll
            for (int jj = 0; jj < 4; jj++) s[cc][jj] = 0.f;

#pragma unroll
        for (int k = 0; k < K; k++) {
            const vf4* zpk = (const vf4*)&zl[k][0][t][0];  // stride per f: 12 vf4
            const vf4* tp0 = (const vf4*)(ThT + ((size_t)k * C + c0 + 0) * F);
            const vf4* tp1 = (const vf4*)(ThT + ((size_t)k * C + c0 + 1) * F);
            const vf4* tp2 = (const vf4*)(ThT + ((size_t)k * C + c0 + 2) * F);
            const vf4* tp3 = (const vf4*)(ThT + ((size_t)k * C + c0 + 3) * F);
#pragma unroll 4
            for (int fq = 0; fq < F / 4; fq++) {
                vf4 z0 = zpk[(4 * fq + 0) * 12];
                vf4 z1 = zpk[(4 * fq + 1) * 12];
                vf4 z2 = zpk[(4 * fq + 2) * 12];
                vf4 z3 = zpk[(4 * fq + 3) * 12];
                vf4 th[4];
                th[0] = tp0[fq];
                th[1] = tp1[fq];
                th[2] = tp2[fq];
                th[3] = tp3[fq];
#pragma unroll
                for (int cc = 0; cc < 4; cc++) {
#pragma unroll
                    for (int jj = 0; jj < 4; jj++)
                        s[cc][jj] += th[cc][0] * z0[jj] + th[cc][1] * z1[jj] +
                                     th[cc][2] * z2[jj] + th[cc][3] * z3[jj];
                }
            }
        }
#pragma unroll
        for (int jj = 0; jj < 4; jj++) {
            int j = j0 + jj;
            if (j < N) {
                float* op = sg + ((size_t)b * N + j) * FT + (size_t)c0 * T + t;
                op[0 * T] = fmaxf(s[0][jj], 0.f);
                op[1 * T] = fmaxf(s[1][jj], 0.f);
                op[2 * T] = fmaxf(s[2][jj], 0.f);
                op[3 * T] = fmaxf(s[3][jj], 0.f);
            }
        }
    }
}

// fallback (workspace too small for Wp): original known-good kernel
__global__ void k_gcnz(const float* __restrict__ x, const float* __restrict__ S,
                       const float* __restrict__ cheb, const float* __restrict__ Theta,
                       float* __restrict__ sg) {
    int blk = blockIdx.x;
    int b = blk / NJB;
    int j0 = (blk % NJB) * JT;
    int tid = threadIdx.x;  // 256

    __shared__ float wl[64][K * JT];
    __shared__ float zl[K][JT][FT];

    float acc[K][JT][3];
#pragma unroll
    for (int k = 0; k < K; k++)
#pragma unroll
        for (int jj = 0; jj < JT; jj++)
#pragma unroll
            for (int r = 0; r < 3; r++) acc[k][jj][r] = 0.f;

    const float* xb = x + (size_t)b * N * FT;

    for (int ic = 0; ic < N; ic += 64) {
        for (int l = tid; l < 64 * K * JT; l += 256) {
            int ii = l / (K * JT);
            int m = l % (K * JT);
            int k = m / JT, jj = m % JT;
            int i = ic + ii, j = j0 + jj;
            float w = 0.f;
            if (i < N && j < N)
                w = cheb[((size_t)k * N + i) * N + j] * S[((size_t)b * N + i) * N + j];
            wl[ii][m] = w;
        }
        __syncthreads();
        int imax = min(64, N - ic);
        for (int ii = 0; ii < imax; ii++) {
            float xv[3];
            const float* xr = xb + (size_t)(ic + ii) * FT;
#pragma unroll
            for (int r = 0; r < 3; r++) xv[r] = xr[tid + 256 * r];
#pragma unroll
            for (int k = 0; k < K; k++)
#pragma unroll
                for (int jj = 0; jj < JT; jj++) {
                    float w = wl[ii][k * JT + jj];
#pragma unroll
                    for (int r = 0; r < 3; r++) acc[k][jj][r] += w * xv[r];
                }
        }
        __syncthreads();
    }

#pragma unroll
    for (int k = 0; k < K; k++)
#pragma unroll
        for (int jj = 0; jj < JT; jj++)
#pragma unroll
            for (int r = 0; r < 3; r++) zl[k][jj][tid + 256 * r] = acc[k][jj][r];
    __syncthreads();

    for (int r = 0; r < 3; r++) {
        int e = tid + 256 * r;  // c*T + t
        int c = e / T;
        int t = e % T;
        float s[JT] = {0.f, 0.f, 0.f, 0.f};
        for (int k = 0; k < K; k++) {
            const float* tp = Theta + (size_t)k * F * C + c;
            const float* zp = &zl[k][0][t];
#pragma unroll 4
            for (int f = 0; f < F; f++) {
                float tv = tp[f * C];
#pragma unroll
                for (int jj = 0; jj < JT; jj++) s[jj] += zp[jj * FT + f * T] * tv;
            }
        }
#pragma unroll
        for (int jj = 0; jj < JT; jj++) {
            int j = j0 + jj;
            if (j < N) sg[((size_t)b * N + j) * FT + e] = fmaxf(s[jj], 0.f);
        }
    }
}

// ---------------- tconv + rconv + relu + LayerNorm (in-place on d_out) ----------------
// v3: 192 threads, thread = (t, ct-group of 4). LDS input reads shared across 4 ct's
// (ds:FMA 1:16), weight float4 loads amortized over RB rows in-register, single
// register-resident LN (4 barriers total, exact two-pass variance).

constexpr int RB = 4;
constexpr int PF = 68;  // padded row: 68%8==4 -> per-t bank shift of 4, <=2-way

__global__ void k_rest(const float* __restrict__ x, const float* __restrict__ twT,
                       const float* __restrict__ tb, const float* __restrict__ rw,
                       const float* __restrict__ rb, const float* __restrict__ gamma,
                       const float* __restrict__ beta, float* __restrict__ io) {
    int blk = blockIdx.x;
    size_t bn0 = (size_t)blk * RB;
    int tid = threadIdx.x;  // 192

    __shared__ float xt[RB][T][PF];       // [t][f], 13.1 KB
    __shared__ float sgt[RB][T + 2][PF];  // [t+1][c], rows 0 & T+1 zero, 15.2 KB
    __shared__ float red0[RB][T][17];     // partial sums over ct
    __shared__ float red1[RB][T][17];
    __shared__ float mus[RB][T], rstds[RB][T];

    for (int l = tid; l < RB * PF; l += 192) {
        int rr = l / PF, c = l % PF;
        sgt[rr][0][c] = 0.f;
        sgt[rr][T + 1][c] = 0.f;
    }
    for (int l = tid; l < RB * FT; l += 192) {
        int rr = l / FT, rem = l % FT;
        int f = rem / T, t = rem % T;  // x/sg layout: [f][t] / [c][t]
        xt[rr][t][f] = x[(bn0 + rr) * FT + rem];
        sgt[rr][t + 1][f] = io[(bn0 + rr) * FT + rem];
    }
    __syncthreads();

    int t = tid % T;    // 0..11
    int cg = tid / T;   // 0..15
    int ct0 = cg * 4;

    float acc[RB][4];
#pragma unroll
    for (int rr = 0; rr < RB; rr++)
#pragma unroll
        for (int q = 0; q < 4; q++) acc[rr][q] = rb[ct0 + q] + tb[ct0 + q];

    // rconv: acc[rr][q] += sum_f rw[ct0+q][f] * xt[rr][t][f]
    {
        const vf4* w0 = (const vf4*)(rw + (size_t)(ct0 + 0) * F);
        const vf4* w1 = (const vf4*)(rw + (size_t)(ct0 + 1) * F);
        const vf4* w2 = (const vf4*)(rw + (size_t)(ct0 + 2) * F);
        const vf4* w3 = (const vf4*)(rw + (size_t)(ct0 + 3) * F);
#pragma unroll 4
        for (int fq = 0; fq < F / 4; fq++) {
            vf4 a = w0[fq], b4 = w1[fq], c4 = w2[fq], d4 = w3[fq];
#pragma unroll
            for (int rr = 0; rr < RB; rr++) {
                vf4 v = *(const vf4*)(&xt[rr][t][fq * 4]);
                acc[rr][0] += a[0] * v[0] + a[1] * v[1] + a[2] * v[2] + a[3] * v[3];
                acc[rr][1] += b4[0] * v[0] + b4[1] * v[1] + b4[2] * v[2] + b4[3] * v[3];
                acc[rr][2] += c4[0] * v[0] + c4[1] * v[1] + c4[2] * v[2] + c4[3] * v[3];
                acc[rr][3] += d4[0] * v[0] + d4[1] * v[1] + d4[2] * v[2] + d4[3] * v[3];
            }
        }
    }
    // tconv: acc[rr][q] += sum_dt sum_c twT[dt][ct0+q][c] * sgt[rr][t+dt][c]
#pragma unroll
    for (int dt = 0; dt < 3; dt++) {
        const vf4* w0 = (const vf4*)(twT + ((size_t)dt * CT + ct0 + 0) * C);
        const vf4* w1 = (const vf4*)(twT + ((size_t)dt * CT + ct0 + 1) * C);
        const vf4* w2 = (const vf4*)(twT + ((size_t)dt * CT + ct0 + 2) * C);
        const vf4* w3 = (const vf4*)(twT + ((size_t)dt * CT + ct0 + 3) * C);
#pragma unroll 4
        for (int fq = 0; fq < C / 4; fq++) {
            vf4 a = w0[fq], b4 = w1[fq], c4 = w2[fq], d4 = w3[fq];
#pragma unroll
            for (int rr = 0; rr < RB; rr++) {
                vf4 v = *(const vf4*)(&sgt[rr][t + dt][fq * 4]);
                acc[rr][0] += a[0] * v[0] + a[1] * v[1] + a[2] * v[2] + a[3] * v[3];
                acc[rr][1] += b4[0] * v[0] + b4[1] * v[1] + b4[2] * v[2] + b4[3] * v[3];
                acc[rr][2] += c4[0] * v[0] + c4[1] * v[1] + c4[2] * v[2] + c4[3] * v[3];
                acc[rr][3] += d4[0] * v[0] + d4[1] * v[1] + d4[2] * v[2] + d4[3] * v[3];
            }
        }
    }

    // relu + LN pass 1 (mean)
#pragma unroll
    for (int rr = 0; rr < RB; rr++) {
        float ps = 0.f;
#pragma unroll
        for (int q = 0; q < 4; q++) {
            float h = fmaxf(acc[rr][q], 0.f);
            acc[rr][q] = h;
            ps += h;
        }
        red0[rr][t][cg] = ps;
    }
    __syncthreads();
    if (tid < RB * T) {
        int rr = tid / T, tt = tid % T;
        float m = 0.f;
#pragma unroll 4
        for (int g = 0; g < 16; g++) m += red0[rr][tt][g];
        mus[rr][tt] = m * (1.f / CT);
    }
    __syncthreads();
    // LN pass 2 (exact variance)
#pragma unroll
    for (int rr = 0; rr < RB; rr++) {
        float m = mus[rr][t];
        float pv = 0.f;
#pragma unroll
        for (int q = 0; q < 4; q++) {
            float d = acc[rr][q] - m;
            pv += d * d;
        }
        red1[rr][t][cg] = pv;
    }
    __syncthreads();
    if (tid < RB * T) {
        int rr = tid / T, tt = tid % T;
        float v = 0.f;
#pragma unroll 4
        for (int g = 0; g < 16; g++) v += red1[rr][tt][g];
        rstds[rr][tt] = rsqrtf(v * (1.f / CT) + LN_EPS);
    }
    __syncthreads();
#pragma unroll
    for (int rr = 0; rr < RB; rr++) {
        float m = mus[rr][t], rs = rstds[rr][t];
        float* iop = io + (bn0 + rr) * FT;
#pragma unroll
        for (int q = 0; q < 4; q++) {
            int ct = ct0 + q;
            iop[ct * T + t] = (acc[rr][q] - m) * rs * gamma[ct] + beta[ct];
        }
    }
}

// ---------------- launch ----------------

extern "C" void kernel_launch(void* const* d_in, const int* in_sizes, int n_in,
                              void* d_out, int out_size, void* d_ws, size_t ws_size,
                              hipStream_t stream) {
    const float* x     = (const float*)d_in[0];
    const float* W1    = (const float*)d_in[1];
    const float* W2    = (const float*)d_in[2];
    const float* W3    = (const float*)d_in[3];
    const float* b_s   = (const float*)d_in[4];
    const float* V_s   = (const float*)d_in[5];
    const float* U1    = (const float*)d_in[6];
    const float* U2    = (const float*)d_in[7];
    const float* U3    = (const float*)d_in[8];
    const float* b_e   = (const float*)d_in[9];
    const float* V_e   = (const float*)d_in[10];
    const float* cheb  = (const float*)d_in[11];
    const float* Theta = (const float*)d_in[12];
    const float* tw    = (const float*)d_in[13];
    const float* tb    = (const float*)d_in[14];
    const float* rw    = (const float*)d_in[15];
    const float* rb    = (const float*)d_in[16];
    const float* gam   = (const float*)d_in[17];
    const float* bet   = (const float*)d_in[18];
    float* out = (float*)d_out;

    float* ws = (float*)d_ws;
    size_t off = 0;
    auto alloc = [&](size_t n) { float* p = ws + off; off += n; return p; };
    float* Sb     = alloc((size_t)B * N * N);
    float* VsT    = alloc((size_t)N * N);
    float* twT    = alloc((size_t)CT * C * 3);
    float* lhs1_e = alloc((size_t)B * T * F);
    float* lhs_e  = alloc((size_t)B * T * N);
    float* rhs_e  = alloc((size_t)B * N * T);
    float* Ebuf   = alloc((size_t)B * T * T);
    float* EW1    = alloc((size_t)B * T);
    float* xw3    = alloc((size_t)B * N * T);
    float* lhs_s  = alloc((size_t)B * N * T);
    float* rhs_s  = alloc((size_t)B * T * N);
    float* ThT    = alloc((size_t)K * F * C);

    // Wp = padded per-jblock cheb (.) S : 72.6 MB, 16B-aligned
    off = (off + 3) & ~(size_t)3;
    size_t nWp = (size_t)B * NJB * N * 12;
    bool useWp = ws_size >= (off + nWp) * sizeof(float);
    float* Wp = ws + off;

    auto g = [](long n) { return dim3((unsigned)((n + 255) / 256)); };

    // temporal attention (k_xdots also precomputes xw3 for spatial attention)
    k_lhs1_e<<<dim3(B * 3), 256, 0, stream>>>(x, U1, lhs1_e);
    k_xdots<<<g((long)B * N * T), 256, 0, stream>>>(x, U3, W3, rhs_e, xw3);
    k_lhs_e<<<g((long)B * T * N), 256, 0, stream>>>(lhs1_e, U2, lhs_e);
    k_tatt<<<B, 256, 0, stream>>>(lhs_e, rhs_e, b_e, V_e, Ebuf);

    // spatial attention (x_TAt folded in)
    k_EW1<<<g((long)B * T), 256, 0, stream>>>(Ebuf, W1, EW1);
    k_lhs_sf<<<B * N, 64, 0, stream>>>(x, EW1, W2, lhs_s);
    k_rhs_s2<<<g((long)B * T * N), 256, 0, stream>>>(xw3, Ebuf, rhs_s);
    k_transposeVs<<<g((long)N * N), 256, 0, stream>>>(V_s, VsT);
    k_twT<<<g((long)CT * C * 3), 256, 0, stream>>>(tw, twT);
    k_thT<<<g((long)K * F * C), 256, 0, stream>>>(Theta, ThT);
    k_sigS<<<B * NAB, 256, 0, stream>>>(lhs_s, rhs_s, b_s, VsT, Sb);
    k_softmax_S<<<g((long)B * N), 256, 0, stream>>>(Sb);

    // graph conv + Theta + relu -> sg staged in d_out
    if (useWp) {
        k_Wp<<<g((long)B * NJB * N * 12), 256, 0, stream>>>(cheb, Sb, Wp);
        k_gcnz_p<<<B * NJB, 256, 0, stream>>>(x, Wp, ThT, out);
    } else {
        k_gcnz<<<B * NJB, 256, 0, stream>>>(x, Sb, cheb, Theta, out);
    }

    // tconv + rconv + relu + LN, in-place on d_out, RB rows per block
    k_rest<<<(B * N) / RB, 192, 0, stream>>>(x, twT, tb, rw, rb, gam, bet, out);
}